// Round 14
// baseline (98.813 us; speedup 1.0000x reference)
//
#include <hip/hip_runtime.h>
#include <hip/hip_bf16.h>
#include <cstdint>

typedef __attribute__((ext_vector_type(8))) __bf16 bf16x8;
typedef __attribute__((ext_vector_type(4))) float f32x4;

static __device__ __forceinline__ unsigned short f2bf(float f) {
  return __builtin_bit_cast(unsigned short, (__bf16)f);
}
static __device__ __forceinline__ unsigned pack2(float a, float b) {
  return (unsigned)f2bf(a) | ((unsigned)f2bf(b) << 16);
}
#define GLDS(src, dst) __builtin_amdgcn_global_load_lds( \
    (const __attribute__((address_space(1))) void*)(src), \
    (__attribute__((address_space(3))) void*)(dst), 16, 0, 0)

// ---------------- small prep kernels ----------------

__global__ void transpose_w_kernel(const float* __restrict__ W1, const float* __restrict__ W2,
                                   unsigned short* __restrict__ W1t, unsigned short* __restrict__ W2t) {
  int i = blockIdx.x * 256 + threadIdx.x;
  int k = i >> 8, n = i & 255;
  W1t[n * 256 + k] = f2bf(W1[k * 256 + n]);
  W2t[n * 256 + k] = f2bf(W2[k * 256 + n]);
}

// x2 = linear2x(sum of 8 bf16 K-split slices of h); vectorized ushort4.
__global__ void upsample_kernel(const unsigned short* __restrict__ hs,  // [8][4096][256]
                                unsigned short* __restrict__ x2b, float* __restrict__ sq) {
  int row = blockIdx.x * 4 + (threadIdx.x >> 6);
  int c = (threadIdx.x & 63) * 4;
  float s = (row + 0.5f) * 0.5f - 0.5f;
  s = fminf(fmaxf(s, 0.0f), 4095.0f);
  float fl = floorf(s);
  int i0 = (int)fl;
  int i1 = min((int)fl + 1, 4095);
  float w = s - fl;
  float v0[4] = {0.f, 0.f, 0.f, 0.f}, v1[4] = {0.f, 0.f, 0.f, 0.f};
  #pragma unroll
  for (int k = 0; k < 8; ++k) {
    ushort4 u0 = *(const ushort4*)&hs[(size_t)k * 4096 * 256 + i0 * 256 + c];
    ushort4 u1 = *(const ushort4*)&hs[(size_t)k * 4096 * 256 + i1 * 256 + c];
    v0[0] += __builtin_bit_cast(float, (unsigned)u0.x << 16);
    v0[1] += __builtin_bit_cast(float, (unsigned)u0.y << 16);
    v0[2] += __builtin_bit_cast(float, (unsigned)u0.z << 16);
    v0[3] += __builtin_bit_cast(float, (unsigned)u0.w << 16);
    v1[0] += __builtin_bit_cast(float, (unsigned)u1.x << 16);
    v1[1] += __builtin_bit_cast(float, (unsigned)u1.y << 16);
    v1[2] += __builtin_bit_cast(float, (unsigned)u1.z << 16);
    v1[3] += __builtin_bit_cast(float, (unsigned)u1.w << 16);
  }
  float p = 0.f;
  ushort4 st;
  unsigned short* sp = (unsigned short*)&st;
  #pragma unroll
  for (int e = 0; e < 4; ++e) {
    float v = v0[e] * (1.0f - w) + v1[e] * w;
    sp[e] = f2bf(v);
    p += v * v;
  }
  *(ushort4*)&x2b[(size_t)row * 256 + c] = st;
  #pragma unroll
  for (int m = 32; m > 0; m >>= 1) p += __shfl_down(p, m, 64);
  if ((threadIdx.x & 63) == 0) sq[row] = p;
}

// ---------------- adj GEMM: BM=256 x BN=256 (full N), 512 threads ------------
// hs_slice(z) = adj[:, z*512:(z+1)*512] @ Tt[:, same]^T. Grid (16 m, 8 z) =
// 128 blocks. B-traffic = 32MB total (vs 64-128 for smaller BM); adj read once.
__launch_bounds__(512)
__global__ void adj_gemm_kernel(const float* __restrict__ adjp,
                                const unsigned short* __restrict__ Ttp,
                                unsigned short* __restrict__ hs) {
  constexpr int NT = 8;                        // KT = 512
  __shared__ alignas(16) unsigned short As[256 * 64];
  __shared__ alignas(16) unsigned short Bs[256 * 64];

  const int tid = threadIdx.x;                 // 0..511
  const int wid = tid >> 6;                    // 0..7
  const int lane = tid & 63;
  const int g = lane >> 4, lr = lane & 15;
  const int wr = wid >> 2;                     // 0..1 (M)
  const int wc = wid & 3;                      // 0..3 (N)
  const int m0 = blockIdx.x * 256;
  const int kbase = blockIdx.y * 512;
  unsigned short* outp = hs + (size_t)blockIdx.y * 4096 * 256;

  const int srow = tid >> 3;                   // 0..63
  const int scp = tid & 7;
  const int ssc = scp ^ (srow & 7);            // pre-swizzled global chunk
  const float* aB[4];
  const unsigned short* bB[4];
  #pragma unroll
  for (int it = 0; it < 4; ++it) {
    aB[it] = adjp + (size_t)(m0 + it * 64 + srow) * 4096 + kbase + ssc * 8;
    bB[it] = Ttp + (size_t)(it * 64 + srow) * 4096 + kbase + ssc * 8;
  }

  f32x4 acc[8][4];
  const f32x4 fzero = {0.f, 0.f, 0.f, 0.f};
  #pragma unroll
  for (int i = 0; i < 8; ++i)
    #pragma unroll
    for (int j = 0; j < 4; ++j) acc[i][j] = fzero;

  #pragma unroll
  for (int t = 0; t < NT; ++t) {
    #pragma unroll
    for (int it = 0; it < 4; ++it)
      GLDS(bB[it] + t * 64, Bs + (size_t)(it * 512 + wid * 64) * 8);
    #pragma unroll
    for (int it = 0; it < 4; ++it) {
      const float* src = aB[it] + t * 64;
      float4 f0 = *(const float4*)src;
      float4 f1 = *(const float4*)(src + 4);
      uint4 pk = { pack2(f0.x, f0.y), pack2(f0.z, f0.w),
                   pack2(f1.x, f1.y), pack2(f1.z, f1.w) };
      *(uint4*)&As[(it * 64 + srow) * 64 + scp * 8] = pk;
    }
    __syncthreads();
    #pragma unroll
    for (int kk = 0; kk < 2; ++kk) {
      const int ch = (kk * 4 + g) ^ (lr & 7);
      bf16x8 b[4];
      #pragma unroll
      for (int j = 0; j < 4; ++j)
        b[j] = *(const bf16x8*)&Bs[(wc * 64 + j * 16 + lr) * 64 + ch * 8];
      #pragma unroll
      for (int i = 0; i < 8; ++i) {
        bf16x8 a = *(const bf16x8*)&As[(wr * 128 + i * 16 + lr) * 64 + ch * 8];
        #pragma unroll
        for (int j = 0; j < 4; ++j)
          acc[i][j] = __builtin_amdgcn_mfma_f32_16x16x32_bf16(a, b[j], acc[i][j], 0, 0, 0);
      }
    }
    __syncthreads();
  }

  // epilogue: bf16 [4096][256] slice
  #pragma unroll
  for (int i = 0; i < 8; ++i) {
    int mrow = m0 + wr * 128 + i * 16 + g * 4;
    #pragma unroll
    for (int j = 0; j < 4; ++j) {
      int col = wc * 64 + j * 16 + lr;
      #pragma unroll
      for (int r = 0; r < 4; ++r)
        outp[(size_t)(mrow + r) * 256 + col] = f2bf(acc[i][j][r]);
    }
  }
}

// ---------------- Gram + fused symmetric argmin, 128^2 tile ------------------
// XCD-swizzled triangle: 2080 = 8*260, t = (b&7)*260 + b>>3 -> consecutive t
// on one XCD share bi => A-tile L2-resident per XCD (T1).
__launch_bounds__(256, 3)
__global__ void gram_kernel(const unsigned short* __restrict__ X,
                            const float* __restrict__ sq,
                            unsigned* __restrict__ pv) {
  __shared__ alignas(16) unsigned short As[128 * 64];
  __shared__ alignas(16) unsigned short Bs[128 * 64];
  __shared__ unsigned mrgr[2][128];
  __shared__ unsigned mrgc[2][128];

  const int tid = threadIdx.x;
  const int wid = tid >> 6;
  const int lane = tid & 63;
  const int g = lane >> 4, lr = lane & 15;
  const int wr = wid >> 1, wc = wid & 1;

  int t0 = blockIdx.x;
  int t = (t0 & 7) * 260 + (t0 >> 3);   // bijective XCD-chunk swizzle (2080=8*260)
  int bi = (int)((sqrtf(8.0f * (float)t + 1.0f) - 1.0f) * 0.5f);
  while ((bi + 1) * (bi + 2) / 2 <= t) ++bi;
  while (bi * (bi + 1) / 2 > t) --bi;
  const int bx = bi;
  const int by = t - bi * (bi + 1) / 2;
  const int m0 = bx * 128;
  const int n0 = by * 128;
  const bool diag = (bx == by);

  const int srow = tid >> 3;
  const int ssc = (tid & 7) ^ (srow & 7);
  const unsigned short* aBase = X + (size_t)(m0 + srow) * 256 + ssc * 8;
  const unsigned short* bBase = X + (size_t)(n0 + srow) * 256 + ssc * 8;
  unsigned short* const aDst = As + (size_t)(tid >> 6) * 512;
  unsigned short* const bDst = Bs + (size_t)(tid >> 6) * 512;
  const unsigned short* const Bsrc = diag ? As : Bs;   // uniform select

  f32x4 acc[4][4];
  const f32x4 fzero = {0.f, 0.f, 0.f, 0.f};
  #pragma unroll
  for (int i = 0; i < 4; ++i)
    #pragma unroll
    for (int j = 0; j < 4; ++j) acc[i][j] = fzero;

  #pragma unroll
  for (int ks = 0; ks < 4; ++ks) {
    #pragma unroll
    for (int it = 0; it < 4; ++it)
      GLDS(aBase + it * 8192 + ks * 64, aDst + it * 2048);
    if (!diag) {
      #pragma unroll
      for (int it = 0; it < 4; ++it)
        GLDS(bBase + it * 8192 + ks * 64, bDst + it * 2048);
    }
    __syncthreads();
    #pragma unroll
    for (int kk = 0; kk < 2; ++kk) {
      const int ch = (kk * 4 + g) ^ (lr & 7);       // row&7 == lr&7 for all frags
      bf16x8 b[4];
      #pragma unroll
      for (int j = 0; j < 4; ++j)
        b[j] = *(const bf16x8*)&Bsrc[(wc * 64 + j * 16 + lr) * 64 + ch * 8];
      #pragma unroll
      for (int i = 0; i < 4; ++i) {
        bf16x8 a = *(const bf16x8*)&As[(wr * 64 + i * 16 + lr) * 64 + ch * 8];
        #pragma unroll
        for (int j = 0; j < 4; ++j)
          acc[i][j] = __builtin_amdgcn_mfma_f32_16x16x32_bf16(a, b[j], acc[i][j], 0, 0, 0);
      }
    }
    __syncthreads();
  }

  int jcol[4];
  float sqj[4];
  unsigned ckey[4];
  #pragma unroll
  for (int j = 0; j < 4; ++j) {
    jcol[j] = n0 + wc * 64 + j * 16 + lr;
    sqj[j] = sq[jcol[j]];
    ckey[j] = 0xFFFFFFFFu;
  }
  #pragma unroll
  for (int i = 0; i < 4; ++i) {
    #pragma unroll
    for (int r = 0; r < 4; ++r) {
      const int lrow = wr * 64 + i * 16 + g * 4 + r;
      const int irow = m0 + lrow;
      const float sqi = sq[irow];
      unsigned rk = 0xFFFFFFFFu;
      #pragma unroll
      for (int j = 0; j < 4; ++j) {
        float v = fmaf(-2.0f, acc[i][j][r], sqi + sqj[j]);   // true d2 >= 0
        unsigned bits = __float_as_uint(v) & 0xFFFFE000u;
        unsigned krow = bits | (unsigned)jcol[j];
        if (diag && jcol[j] == irow) krow = 0xFFFFFFFFu;
        rk = min(rk, krow);
        if (!diag) ckey[j] = min(ckey[j], bits | (unsigned)irow);
      }
      #pragma unroll
      for (int m = 1; m < 16; m <<= 1)
        rk = min(rk, (unsigned)__shfl_xor((int)rk, m, 64));
      if (lr == 0) mrgr[wc][lrow] = rk;
    }
  }
  if (!diag) {
    #pragma unroll
    for (int j = 0; j < 4; ++j) {
      ckey[j] = min(ckey[j], (unsigned)__shfl_xor((int)ckey[j], 16, 64));
      ckey[j] = min(ckey[j], (unsigned)__shfl_xor((int)ckey[j], 32, 64));
      if (g == 0) mrgc[wr][wc * 64 + j * 16 + lr] = ckey[j];
    }
  }
  __syncthreads();
  if (tid < 128) {
    pv[(size_t)by * 8192 + m0 + tid] = min(mrgr[0][tid], mrgr[1][tid]);
  } else if (!diag) {
    int c = tid - 128;
    pv[(size_t)(64 + bx) * 8192 + n0 + c] = min(mrgc[0][c], mrgc[1][c]);
  }
}

// ---------------- single-buffer GEMM-NT (C = A * B^T), unrolled K ------------
// EPI 0: Cf[m][n] fp32.  EPI 1: Ct[n][m] bf16 transposed.
// GATHER: inline per-block argmin-reduce over pv, then A row r reads row nn[r].
template <int BM, int BN, int WAVES_M, int KT, int EPI, bool AF32, bool GATHER>
__launch_bounds__(256)
__global__ void gemm_nt_kernel(const void* __restrict__ Ap, int lda,
                               const unsigned short* __restrict__ Bp, int ldb,
                               int M, int N,
                               float* __restrict__ Cf,
                               unsigned short* __restrict__ Cb,
                               const unsigned* __restrict__ pv) {
  constexpr int BK = 64;
  constexpr int NT = KT / BK;
  constexpr int WAVES_N = 4 / WAVES_M;
  constexpr int WM = BM / WAVES_M;
  constexpr int WN = BN / WAVES_N;
  constexpr int FM = WM / 16;
  constexpr int FN = WN / 16;
  constexpr int ASLOT = BM * 8;
  constexpr int AITER = (ASLOT + 255) / 256;
  constexpr int BITER = (BN * 8) / 256;

  __shared__ alignas(16) unsigned short As[BM * BK];
  __shared__ alignas(16) unsigned short Bs[BN * BK];
  __shared__ unsigned redp[GATHER ? 4 * 64 : 1];
  __shared__ unsigned pckl[GATHER ? 64 : 1];

  const int tid = threadIdx.x;
  const int wid = tid >> 6;
  const int lane = tid & 63;
  const int g = lane >> 4;
  const int lr = lane & 15;
  const int wr = wid / WAVES_N;
  const int wc = wid % WAVES_N;
  const int m0 = blockIdx.x * BM;
  const int n0 = blockIdx.y * BN;

  // ---- inline NN-index reduce (GATHER): rows m0..m0+63 share chunk cr ----
  if constexpr (GATHER) {
    static_assert(!GATHER || BM == 64, "inline reduce assumes BM==64");
    const int row = tid & 63;          // lane
    const int part = tid >> 6;         // wave
    const int cr = m0 >> 7;            // block-uniform chunk
    unsigned best = 0xFFFFFFFFu;
    #pragma unroll
    for (int s8 = 0; s8 < 16; ++s8) {
      int s = part * 16 + s8;
      int slot = s + (s > cr ? 64 : 0);
      best = min(best, pv[(size_t)slot * 8192 + m0 + row]);
    }
    redp[part * 64 + row] = best;
    __syncthreads();
    if (tid < 64)
      pckl[tid] = min(min(redp[tid], redp[64 + tid]),
                      min(redp[128 + tid], redp[192 + tid])) & 0x1FFFu;
    __syncthreads();
  }

  const int srow = tid >> 3;
  const int ssc = (tid & 7) ^ (srow & 7);
  const float* aBF[AITER];
  const unsigned short* aBH[AITER];
  #pragma unroll
  for (int it = 0; it < AITER; ++it) {
    int r = m0 + srow + it * 32;
    if constexpr (AF32) {
      aBF[it] = (const float*)Ap + (size_t)r * (size_t)lda + ssc * 8;
    } else {
      int sr = GATHER ? (int)pckl[srow + it * 32] : r;
      aBH[it] = (const unsigned short*)Ap + (size_t)sr * (size_t)lda + ssc * 8;
    }
  }
  const unsigned short* bBase = Bp + (size_t)(n0 + srow) * (size_t)ldb + ssc * 8;
  unsigned short* const sDst = As + (size_t)wid * 512;
  unsigned short* const bDst = Bs + (size_t)wid * 512;

  f32x4 acc[FM][FN];
  const f32x4 fzero = {0.f, 0.f, 0.f, 0.f};
  #pragma unroll
  for (int i = 0; i < FM; ++i)
    #pragma unroll
    for (int j = 0; j < FN; ++j) acc[i][j] = fzero;

  #pragma unroll
  for (int t = 0; t < NT; ++t) {
    #pragma unroll
    for (int it = 0; it < BITER; ++it)
      GLDS(bBase + (size_t)it * 32 * ldb + t * 64, bDst + it * 2048);
    if constexpr (AF32) {
      #pragma unroll
      for (int it = 0; it < AITER; ++it) {
        if (ASLOT % 256 == 0 || it * 256 + tid < ASLOT) {
          const float* src = aBF[it] + t * 64;
          float4 f0 = *(const float4*)src;
          float4 f1 = *(const float4*)(src + 4);
          uint4 pk = { pack2(f0.x, f0.y), pack2(f0.z, f0.w),
                       pack2(f1.x, f1.y), pack2(f1.z, f1.w) };
          *(uint4*)&As[(it * 32 + srow) * BK + (tid & 7) * 8] = pk;
        }
      }
    } else {
      #pragma unroll
      for (int it = 0; it < AITER; ++it)
        GLDS(aBH[it] + t * 64, sDst + it * 2048);
    }
    __syncthreads();
    #pragma unroll
    for (int kk = 0; kk < 2; ++kk) {
      const int ch = (kk * 4 + g) ^ (lr & 7);
      bf16x8 a[FM], b[FN];
      #pragma unroll
      for (int i = 0; i < FM; ++i)
        a[i] = *(const bf16x8*)&As[(wr * WM + i * 16 + lr) * BK + ch * 8];
      #pragma unroll
      for (int j = 0; j < FN; ++j)
        b[j] = *(const bf16x8*)&Bs[(wc * WN + j * 16 + lr) * BK + ch * 8];
      #pragma unroll
      for (int i = 0; i < FM; ++i)
        #pragma unroll
        for (int j = 0; j < FN; ++j)
          acc[i][j] = __builtin_amdgcn_mfma_f32_16x16x32_bf16(a[i], b[j], acc[i][j], 0, 0, 0);
    }
    __syncthreads();
  }

  const int rowb = wr * WM;
  const int colb = wc * WN;
  if constexpr (EPI == 0) {
    #pragma unroll
    for (int i = 0; i < FM; ++i) {
      int mrow = m0 + rowb + i * 16 + g * 4;
      #pragma unroll
      for (int j = 0; j < FN; ++j) {
        int col = n0 + colb + j * 16 + lr;
        #pragma unroll
        for (int r = 0; r < 4; ++r)
          Cf[(size_t)(mrow + r) * N + col] = acc[i][j][r];
      }
    }
  } else {
    #pragma unroll
    for (int i = 0; i < FM; ++i) {
      int mrow = m0 + rowb + i * 16 + g * 4;
      #pragma unroll
      for (int j = 0; j < FN; ++j) {
        int col = n0 + colb + j * 16 + lr;
        ushort4 st;
        st.x = f2bf(acc[i][j][0]);
        st.y = f2bf(acc[i][j][1]);
        st.z = f2bf(acc[i][j][2]);
        st.w = f2bf(acc[i][j][3]);
        *(ushort4*)&Cb[(size_t)col * M + mrow] = st;
      }
    }
  }
}

// ---------------- launch ----------------

extern "C" void kernel_launch(void* const* d_in, const int* in_sizes, int n_in,
                              void* d_out, int out_size, void* d_ws, size_t ws_size,
                              hipStream_t stream) {
  (void)in_sizes; (void)n_in; (void)out_size; (void)ws_size;
  const float* x   = (const float*)d_in[0];   // [4096][256]
  const float* adj = (const float*)d_in[1];   // [4096][4096]
  const float* W1  = (const float*)d_in[2];   // [256][256]
  const float* W2  = (const float*)d_in[3];   // [256][256]
  float* out = (float*)d_out;                 // [8192][256]

  char* p = (char*)d_ws;
  unsigned short* Tt  = (unsigned short*)p;  p += 4096 * 256 * 2;     // 2MB  (x@W1)^T [256][4096]
  char* R             = p;                   p += 16 * 1024 * 1024;   // 16MB shared-lifetime region
  unsigned short* x2b = (unsigned short*)p;  p += 8192 * 256 * 2;     // 4MB
  float* sqv          = (float*)p;           p += 8192 * 4;
  unsigned short* W1t = (unsigned short*)p;  p += 256 * 256 * 2;
  unsigned short* W2t = (unsigned short*)p;  p += 256 * 256 * 2;

  // region R overlays (disjoint lifetimes):
  unsigned short* hs = (unsigned short*)R;   // [8][4096][256] bf16 (adj-gemm -> upsample), 16MB
  unsigned* pv       = (unsigned*)R;         // [128][8192] u32 keys (gram -> out-gemm), 4MB

  transpose_w_kernel<<<256, 256, 0, stream>>>(W1, W2, W1t, W2t);

  // Tt = (x @ W1)^T : M=4096 N=256 K=256 (EPI1 transposed bf16 out)
  gemm_nt_kernel<64, 64, 4, 256, 1, true, false><<<dim3(64, 4), 256, 0, stream>>>(
      x, 256, W1t, 256, 4096, 256, nullptr, Tt, nullptr);

  // h(k-split) = adj @ Tt^T : BM=256 x full-N=256, 512thr, K split 8x512
  // -> 128 blocks; total read 96MB (adj once + 32MB Tt restage)
  adj_gemm_kernel<<<dim3(16, 8), 512, 0, stream>>>(adj, Tt, hs);

  upsample_kernel<<<2048, 256, 0, stream>>>(hs, x2b, sqv);

  // gram triangle (2080 blocks, XCD-swizzled); pv needs NO init
  gram_kernel<<<2080, 256, 0, stream>>>(x2b, sqv, pv);

  // out = x2[nn] @ W2 : inline argmin-reduce + gathered-A GEMM -> d_out
  gemm_nt_kernel<64, 64, 4, 256, 0, false, true><<<dim3(128, 4), 256, 0, stream>>>(
      x2b, 256, W2t, 256, 8192, 256, out, nullptr, pv);
}

// Round 15
// 96.562 us; speedup vs baseline: 1.0233x; 1.0233x over previous
//
#include <hip/hip_runtime.h>
#include <hip/hip_bf16.h>
#include <cstdint>

typedef __attribute__((ext_vector_type(8))) __bf16 bf16x8;
typedef __attribute__((ext_vector_type(4))) float f32x4;

static __device__ __forceinline__ unsigned short f2bf(float f) {
  return __builtin_bit_cast(unsigned short, (__bf16)f);
}
static __device__ __forceinline__ unsigned pack2(float a, float b) {
  return (unsigned)f2bf(a) | ((unsigned)f2bf(b) << 16);
}
#define GLDS(src, dst) __builtin_amdgcn_global_load_lds( \
    (const __attribute__((address_space(1))) void*)(src), \
    (__attribute__((address_space(3))) void*)(dst), 16, 0, 0)

// ---------------- small prep kernels ----------------

__global__ void transpose_w_kernel(const float* __restrict__ W1, const float* __restrict__ W2,
                                   unsigned short* __restrict__ W1t, unsigned short* __restrict__ W2t) {
  int i = blockIdx.x * 256 + threadIdx.x;
  int k = i >> 8, n = i & 255;
  W1t[n * 256 + k] = f2bf(W1[k * 256 + n]);
  W2t[n * 256 + k] = f2bf(W2[k * 256 + n]);
}

// adj fp32 -> bf16, pure stream (same rounding as the in-GEMM pack2 -> bit-identical)
__global__ void cvt_adj_kernel(const float* __restrict__ a, unsigned short* __restrict__ ab) {
  size_t i = ((size_t)blockIdx.x * 256 + threadIdx.x) * 8;
  const size_t stride = (size_t)2048 * 256 * 8;
  #pragma unroll
  for (int t = 0; t < 4; ++t, i += stride) {
    float4 f0 = *(const float4*)(a + i);
    float4 f1 = *(const float4*)(a + i + 4);
    uint4 pk = { pack2(f0.x, f0.y), pack2(f0.z, f0.w),
                 pack2(f1.x, f1.y), pack2(f1.z, f1.w) };
    *(uint4*)(ab + i) = pk;
  }
}

// x2 = linear2x(sum of 8 bf16 K-split slices of h); vectorized ushort4.
__global__ void upsample_kernel(const unsigned short* __restrict__ hs,  // [8][4096][256]
                                unsigned short* __restrict__ x2b, float* __restrict__ sq) {
  int row = blockIdx.x * 4 + (threadIdx.x >> 6);
  int c = (threadIdx.x & 63) * 4;
  float s = (row + 0.5f) * 0.5f - 0.5f;
  s = fminf(fmaxf(s, 0.0f), 4095.0f);
  float fl = floorf(s);
  int i0 = (int)fl;
  int i1 = min((int)fl + 1, 4095);
  float w = s - fl;
  float v0[4] = {0.f, 0.f, 0.f, 0.f}, v1[4] = {0.f, 0.f, 0.f, 0.f};
  #pragma unroll
  for (int k = 0; k < 8; ++k) {
    ushort4 u0 = *(const ushort4*)&hs[(size_t)k * 4096 * 256 + i0 * 256 + c];
    ushort4 u1 = *(const ushort4*)&hs[(size_t)k * 4096 * 256 + i1 * 256 + c];
    v0[0] += __builtin_bit_cast(float, (unsigned)u0.x << 16);
    v0[1] += __builtin_bit_cast(float, (unsigned)u0.y << 16);
    v0[2] += __builtin_bit_cast(float, (unsigned)u0.z << 16);
    v0[3] += __builtin_bit_cast(float, (unsigned)u0.w << 16);
    v1[0] += __builtin_bit_cast(float, (unsigned)u1.x << 16);
    v1[1] += __builtin_bit_cast(float, (unsigned)u1.y << 16);
    v1[2] += __builtin_bit_cast(float, (unsigned)u1.z << 16);
    v1[3] += __builtin_bit_cast(float, (unsigned)u1.w << 16);
  }
  float p = 0.f;
  ushort4 st;
  unsigned short* sp = (unsigned short*)&st;
  #pragma unroll
  for (int e = 0; e < 4; ++e) {
    float v = v0[e] * (1.0f - w) + v1[e] * w;
    sp[e] = f2bf(v);
    p += v * v;
  }
  *(ushort4*)&x2b[(size_t)row * 256 + c] = st;
  #pragma unroll
  for (int m = 32; m > 0; m >>= 1) p += __shfl_down(p, m, 64);
  if ((threadIdx.x & 63) == 0) sq[row] = p;
}

// ---------------- Gram + fused symmetric argmin, 128^2 tile ------------------
__launch_bounds__(256, 3)
__global__ void gram_kernel(const unsigned short* __restrict__ X,
                            const float* __restrict__ sq,
                            unsigned* __restrict__ pv) {
  __shared__ alignas(16) unsigned short As[128 * 64];
  __shared__ alignas(16) unsigned short Bs[128 * 64];
  __shared__ unsigned mrgr[2][128];
  __shared__ unsigned mrgc[2][128];

  const int tid = threadIdx.x;
  const int wid = tid >> 6;
  const int lane = tid & 63;
  const int g = lane >> 4, lr = lane & 15;
  const int wr = wid >> 1, wc = wid & 1;

  int t = blockIdx.x;            // triangular decode, bj <= bi
  int bi = (int)((sqrtf(8.0f * (float)t + 1.0f) - 1.0f) * 0.5f);
  while ((bi + 1) * (bi + 2) / 2 <= t) ++bi;
  while (bi * (bi + 1) / 2 > t) --bi;
  const int bx = bi;
  const int by = t - bi * (bi + 1) / 2;
  const int m0 = bx * 128;
  const int n0 = by * 128;
  const bool diag = (bx == by);

  const int srow = tid >> 3;
  const int ssc = (tid & 7) ^ (srow & 7);
  const unsigned short* aBase = X + (size_t)(m0 + srow) * 256 + ssc * 8;
  const unsigned short* bBase = X + (size_t)(n0 + srow) * 256 + ssc * 8;
  unsigned short* const aDst = As + (size_t)(tid >> 6) * 512;
  unsigned short* const bDst = Bs + (size_t)(tid >> 6) * 512;
  const unsigned short* const Bsrc = diag ? As : Bs;   // uniform select

  f32x4 acc[4][4];
  const f32x4 fzero = {0.f, 0.f, 0.f, 0.f};
  #pragma unroll
  for (int i = 0; i < 4; ++i)
    #pragma unroll
    for (int j = 0; j < 4; ++j) acc[i][j] = fzero;

  #pragma unroll
  for (int ks = 0; ks < 4; ++ks) {
    #pragma unroll
    for (int it = 0; it < 4; ++it)
      GLDS(aBase + it * 8192 + ks * 64, aDst + it * 2048);
    if (!diag) {
      #pragma unroll
      for (int it = 0; it < 4; ++it)
        GLDS(bBase + it * 8192 + ks * 64, bDst + it * 2048);
    }
    __syncthreads();
    #pragma unroll
    for (int kk = 0; kk < 2; ++kk) {
      const int ch = (kk * 4 + g) ^ (lr & 7);       // row&7 == lr&7 for all frags
      bf16x8 b[4];
      #pragma unroll
      for (int j = 0; j < 4; ++j)
        b[j] = *(const bf16x8*)&Bsrc[(wc * 64 + j * 16 + lr) * 64 + ch * 8];
      #pragma unroll
      for (int i = 0; i < 4; ++i) {
        bf16x8 a = *(const bf16x8*)&As[(wr * 64 + i * 16 + lr) * 64 + ch * 8];
        #pragma unroll
        for (int j = 0; j < 4; ++j)
          acc[i][j] = __builtin_amdgcn_mfma_f32_16x16x32_bf16(a, b[j], acc[i][j], 0, 0, 0);
      }
    }
    __syncthreads();
  }

  int jcol[4];
  float sqj[4];
  unsigned ckey[4];
  #pragma unroll
  for (int j = 0; j < 4; ++j) {
    jcol[j] = n0 + wc * 64 + j * 16 + lr;
    sqj[j] = sq[jcol[j]];
    ckey[j] = 0xFFFFFFFFu;
  }
  #pragma unroll
  for (int i = 0; i < 4; ++i) {
    #pragma unroll
    for (int r = 0; r < 4; ++r) {
      const int lrow = wr * 64 + i * 16 + g * 4 + r;
      const int irow = m0 + lrow;
      const float sqi = sq[irow];
      unsigned rk = 0xFFFFFFFFu;
      #pragma unroll
      for (int j = 0; j < 4; ++j) {
        float v = fmaf(-2.0f, acc[i][j][r], sqi + sqj[j]);   // true d2 >= 0
        unsigned bits = __float_as_uint(v) & 0xFFFFE000u;
        unsigned krow = bits | (unsigned)jcol[j];
        if (diag && jcol[j] == irow) krow = 0xFFFFFFFFu;
        rk = min(rk, krow);
        if (!diag) ckey[j] = min(ckey[j], bits | (unsigned)irow);
      }
      #pragma unroll
      for (int m = 1; m < 16; m <<= 1)
        rk = min(rk, (unsigned)__shfl_xor((int)rk, m, 64));
      if (lr == 0) mrgr[wc][lrow] = rk;
    }
  }
  if (!diag) {
    #pragma unroll
    for (int j = 0; j < 4; ++j) {
      ckey[j] = min(ckey[j], (unsigned)__shfl_xor((int)ckey[j], 16, 64));
      ckey[j] = min(ckey[j], (unsigned)__shfl_xor((int)ckey[j], 32, 64));
      if (g == 0) mrgc[wr][wc * 64 + j * 16 + lr] = ckey[j];
    }
  }
  __syncthreads();
  if (tid < 128) {
    pv[(size_t)by * 8192 + m0 + tid] = min(mrgr[0][tid], mrgr[1][tid]);
  } else if (!diag) {
    int c = tid - 128;
    pv[(size_t)(64 + bx) * 8192 + n0 + c] = min(mrgc[0][c], mrgc[1][c]);
  }
}

// ---------------- single-buffer GEMM-NT (C = A * B^T), unrolled K ------------
// EPI 0: Cf[m][n] fp32.  EPI 1: Ct[n][m] bf16 transposed.
// EPI 3: Cb[m][n] bf16, K-split via blockIdx.z (kbase = z*KT, out += z*M*N).
// GATHER: inline per-block argmin-reduce over pv, then A row r reads row nn[r].
template <int BM, int BN, int WAVES_M, int KT, int EPI, bool AF32, bool GATHER>
__launch_bounds__(256)
__global__ void gemm_nt_kernel(const void* __restrict__ Ap, int lda,
                               const unsigned short* __restrict__ Bp, int ldb,
                               int M, int N,
                               float* __restrict__ Cf,
                               unsigned short* __restrict__ Cb,
                               const unsigned* __restrict__ pv) {
  constexpr int BK = 64;
  constexpr int NT = KT / BK;
  constexpr int WAVES_N = 4 / WAVES_M;
  constexpr int WM = BM / WAVES_M;
  constexpr int WN = BN / WAVES_N;
  constexpr int FM = WM / 16;
  constexpr int FN = WN / 16;
  constexpr int ASLOT = BM * 8;
  constexpr int AITER = (ASLOT + 255) / 256;
  constexpr int BITER = (BN * 8) / 256;

  __shared__ alignas(16) unsigned short As[BM * BK];
  __shared__ alignas(16) unsigned short Bs[BN * BK];
  __shared__ unsigned redp[GATHER ? 4 * 64 : 1];
  __shared__ unsigned pckl[GATHER ? 64 : 1];

  const int tid = threadIdx.x;
  const int wid = tid >> 6;
  const int lane = tid & 63;
  const int g = lane >> 4;
  const int lr = lane & 15;
  const int wr = wid / WAVES_N;
  const int wc = wid % WAVES_N;
  const int m0 = blockIdx.x * BM;
  const int n0 = blockIdx.y * BN;
  const int kbase = (EPI == 3) ? blockIdx.z * KT : 0;
  if constexpr (EPI == 3) Cb += (size_t)blockIdx.z * (size_t)M * (size_t)N;

  // ---- inline NN-index reduce (GATHER): rows m0..m0+63 share chunk cr ----
  if constexpr (GATHER) {
    static_assert(!GATHER || BM == 64, "inline reduce assumes BM==64");
    const int row = tid & 63;          // lane
    const int part = tid >> 6;         // wave
    const int cr = m0 >> 7;            // block-uniform chunk
    unsigned best = 0xFFFFFFFFu;
    #pragma unroll
    for (int s8 = 0; s8 < 16; ++s8) {
      int s = part * 16 + s8;
      int slot = s + (s > cr ? 64 : 0);
      best = min(best, pv[(size_t)slot * 8192 + m0 + row]);
    }
    redp[part * 64 + row] = best;
    __syncthreads();
    if (tid < 64)
      pckl[tid] = min(min(redp[tid], redp[64 + tid]),
                      min(redp[128 + tid], redp[192 + tid])) & 0x1FFFu;
    __syncthreads();
  }

  const int srow = tid >> 3;
  const int ssc = (tid & 7) ^ (srow & 7);
  const float* aBF[AITER];
  const unsigned short* aBH[AITER];
  #pragma unroll
  for (int it = 0; it < AITER; ++it) {
    int r = m0 + srow + it * 32;
    if constexpr (AF32) {
      aBF[it] = (const float*)Ap + (size_t)r * (size_t)lda + kbase + ssc * 8;
    } else {
      int sr = GATHER ? (int)pckl[srow + it * 32] : r;
      aBH[it] = (const unsigned short*)Ap + (size_t)sr * (size_t)lda + kbase + ssc * 8;
    }
  }
  const unsigned short* bBase = Bp + (size_t)(n0 + srow) * (size_t)ldb + kbase + ssc * 8;
  unsigned short* const sDst = As + (size_t)wid * 512;
  unsigned short* const bDst = Bs + (size_t)wid * 512;

  f32x4 acc[FM][FN];
  const f32x4 fzero = {0.f, 0.f, 0.f, 0.f};
  #pragma unroll
  for (int i = 0; i < FM; ++i)
    #pragma unroll
    for (int j = 0; j < FN; ++j) acc[i][j] = fzero;

  #pragma unroll
  for (int t = 0; t < NT; ++t) {
    #pragma unroll
    for (int it = 0; it < BITER; ++it)
      GLDS(bBase + (size_t)it * 32 * ldb + t * 64, bDst + it * 2048);
    if constexpr (AF32) {
      #pragma unroll
      for (int it = 0; it < AITER; ++it) {
        if (ASLOT % 256 == 0 || it * 256 + tid < ASLOT) {
          const float* src = aBF[it] + t * 64;
          float4 f0 = *(const float4*)src;
          float4 f1 = *(const float4*)(src + 4);
          uint4 pk = { pack2(f0.x, f0.y), pack2(f0.z, f0.w),
                       pack2(f1.x, f1.y), pack2(f1.z, f1.w) };
          *(uint4*)&As[(it * 32 + srow) * BK + (tid & 7) * 8] = pk;
        }
      }
    } else {
      #pragma unroll
      for (int it = 0; it < AITER; ++it)
        GLDS(aBH[it] + t * 64, sDst + it * 2048);
    }
    __syncthreads();
    #pragma unroll
    for (int kk = 0; kk < 2; ++kk) {
      const int ch = (kk * 4 + g) ^ (lr & 7);
      bf16x8 a[FM], b[FN];
      #pragma unroll
      for (int i = 0; i < FM; ++i)
        a[i] = *(const bf16x8*)&As[(wr * WM + i * 16 + lr) * BK + ch * 8];
      #pragma unroll
      for (int j = 0; j < FN; ++j)
        b[j] = *(const bf16x8*)&Bs[(wc * WN + j * 16 + lr) * BK + ch * 8];
      #pragma unroll
      for (int i = 0; i < FM; ++i)
        #pragma unroll
        for (int j = 0; j < FN; ++j)
          acc[i][j] = __builtin_amdgcn_mfma_f32_16x16x32_bf16(a[i], b[j], acc[i][j], 0, 0, 0);
    }
    __syncthreads();
  }

  const int rowb = wr * WM;
  const int colb = wc * WN;
  if constexpr (EPI == 0) {
    #pragma unroll
    for (int i = 0; i < FM; ++i) {
      int mrow = m0 + rowb + i * 16 + g * 4;
      #pragma unroll
      for (int j = 0; j < FN; ++j) {
        int col = n0 + colb + j * 16 + lr;
        #pragma unroll
        for (int r = 0; r < 4; ++r)
          Cf[(size_t)(mrow + r) * N + col] = acc[i][j][r];
      }
    }
  } else if constexpr (EPI == 1) {
    #pragma unroll
    for (int i = 0; i < FM; ++i) {
      int mrow = m0 + rowb + i * 16 + g * 4;
      #pragma unroll
      for (int j = 0; j < FN; ++j) {
        int col = n0 + colb + j * 16 + lr;
        ushort4 st;
        st.x = f2bf(acc[i][j][0]);
        st.y = f2bf(acc[i][j][1]);
        st.z = f2bf(acc[i][j][2]);
        st.w = f2bf(acc[i][j][3]);
        *(ushort4*)&Cb[(size_t)col * M + mrow] = st;
      }
    }
  } else {
    #pragma unroll
    for (int i = 0; i < FM; ++i) {
      int mrow = m0 + rowb + i * 16 + g * 4;
      #pragma unroll
      for (int j = 0; j < FN; ++j) {
        int col = n0 + colb + j * 16 + lr;
        #pragma unroll
        for (int r = 0; r < 4; ++r)
          Cb[(size_t)(mrow + r) * N + col] = f2bf(acc[i][j][r]);
      }
    }
  }
}

// ---------------- launch ----------------

extern "C" void kernel_launch(void* const* d_in, const int* in_sizes, int n_in,
                              void* d_out, int out_size, void* d_ws, size_t ws_size,
                              hipStream_t stream) {
  (void)in_sizes; (void)n_in; (void)out_size;
  const float* x   = (const float*)d_in[0];   // [4096][256]
  const float* adj = (const float*)d_in[1];   // [4096][4096]
  const float* W1  = (const float*)d_in[2];   // [256][256]
  const float* W2  = (const float*)d_in[3];   // [256][256]
  float* out = (float*)d_out;                 // [8192][256]

  char* p = (char*)d_ws;
  unsigned short* Tt  = (unsigned short*)p;  p += 4096 * 256 * 2;     // 2MB
  unsigned short* x2b = (unsigned short*)p;  p += 8192 * 256 * 2;     // 4MB
  float* sqv          = (float*)p;           p += 8192 * 4;
  unsigned short* W1t = (unsigned short*)p;  p += 256 * 256 * 2;
  unsigned short* W2t = (unsigned short*)p;  p += 256 * 256 * 2;
  char* R             = p;                   p += 16 * 1024 * 1024;   // hs(16MB)/pv(4MB)
  unsigned short* adjb = (unsigned short*)p; p += (size_t)4096 * 4096 * 2;  // 32MB

  const bool bf16path = ((size_t)(p - (char*)d_ws) <= ws_size);

  // region R overlays (disjoint lifetimes):
  unsigned short* hs = (unsigned short*)R;   // [8][4096][256] bf16, 16MB
  unsigned* pv       = (unsigned*)R;         // [128][8192] u32 keys, 4MB

  transpose_w_kernel<<<256, 256, 0, stream>>>(W1, W2, W1t, W2t);

  // Tt = (x @ W1)^T : M=4096 N=256 K=256 (EPI1 transposed bf16 out)
  gemm_nt_kernel<64, 64, 4, 256, 1, true, false><<<dim3(64, 4), 256, 0, stream>>>(
      x, 256, W1t, 256, 4096, 256, nullptr, Tt, nullptr);

  if (bf16path) {
    // stream-convert adj once (bit-identical rounding to in-GEMM pack2)
    cvt_adj_kernel<<<2048, 256, 0, stream>>>(adj, adjb);
    // h(k-split) = adjb @ Tt^T : all-bf16, global_load_lds both operands
    gemm_nt_kernel<128, 128, 2, 512, 3, false, false><<<dim3(32, 2, 8), 256, 0, stream>>>(
        adjb, 4096, Tt, 4096, 4096, 256, nullptr, hs, nullptr);
  } else {
    // fallback (scratch-limited): fp32-A path, same shape
    gemm_nt_kernel<128, 128, 2, 512, 3, true, false><<<dim3(32, 2, 8), 256, 0, stream>>>(
        adj, 4096, Tt, 4096, 4096, 256, nullptr, hs, nullptr);
  }

  upsample_kernel<<<2048, 256, 0, stream>>>(hs, x2b, sqv);

  // gram triangle (2080 blocks); pv needs NO init (bounded inline reduce)
  gram_kernel<<<2080, 256, 0, stream>>>(x2b, sqv, pv);

  // out = x2[nn] @ W2 : inline argmin-reduce + gathered-A GEMM -> d_out
  gemm_nt_kernel<64, 64, 4, 256, 0, false, true><<<dim3(128, 4), 256, 0, stream>>>(
      x2b, 256, W2t, 256, 8192, 256, out, nullptr, pv);
}

// Round 16
// 87.629 us; speedup vs baseline: 1.1276x; 1.1019x over previous
//
#include <hip/hip_runtime.h>
#include <hip/hip_bf16.h>
#include <cstdint>

typedef __attribute__((ext_vector_type(8))) __bf16 bf16x8;
typedef __attribute__((ext_vector_type(4))) float f32x4;

static __device__ __forceinline__ unsigned short f2bf(float f) {
  return __builtin_bit_cast(unsigned short, (__bf16)f);
}
static __device__ __forceinline__ unsigned pack2(float a, float b) {
  return (unsigned)f2bf(a) | ((unsigned)f2bf(b) << 16);
}
#define GLDS(src, dst) __builtin_amdgcn_global_load_lds( \
    (const __attribute__((address_space(1))) void*)(src), \
    (__attribute__((address_space(3))) void*)(dst), 16, 0, 0)

// ---------------- small prep kernels ----------------

__global__ void transpose_w_kernel(const float* __restrict__ W1, const float* __restrict__ W2,
                                   unsigned short* __restrict__ W1t, unsigned short* __restrict__ W2t) {
  int i = blockIdx.x * 256 + threadIdx.x;
  int k = i >> 8, n = i & 255;
  W1t[n * 256 + k] = f2bf(W1[k * 256 + n]);
  W2t[n * 256 + k] = f2bf(W2[k * 256 + n]);
}

// x2 = linear2x(sum of 8 bf16 K-split slices of h); vectorized ushort4.
__global__ void upsample_kernel(const unsigned short* __restrict__ hs,  // [8][4096][256]
                                unsigned short* __restrict__ x2b, float* __restrict__ sq) {
  int row = blockIdx.x * 4 + (threadIdx.x >> 6);
  int c = (threadIdx.x & 63) * 4;
  float s = (row + 0.5f) * 0.5f - 0.5f;
  s = fminf(fmaxf(s, 0.0f), 4095.0f);
  float fl = floorf(s);
  int i0 = (int)fl;
  int i1 = min((int)fl + 1, 4095);
  float w = s - fl;
  float v0[4] = {0.f, 0.f, 0.f, 0.f}, v1[4] = {0.f, 0.f, 0.f, 0.f};
  #pragma unroll
  for (int k = 0; k < 8; ++k) {
    ushort4 u0 = *(const ushort4*)&hs[(size_t)k * 4096 * 256 + i0 * 256 + c];
    ushort4 u1 = *(const ushort4*)&hs[(size_t)k * 4096 * 256 + i1 * 256 + c];
    v0[0] += __builtin_bit_cast(float, (unsigned)u0.x << 16);
    v0[1] += __builtin_bit_cast(float, (unsigned)u0.y << 16);
    v0[2] += __builtin_bit_cast(float, (unsigned)u0.z << 16);
    v0[3] += __builtin_bit_cast(float, (unsigned)u0.w << 16);
    v1[0] += __builtin_bit_cast(float, (unsigned)u1.x << 16);
    v1[1] += __builtin_bit_cast(float, (unsigned)u1.y << 16);
    v1[2] += __builtin_bit_cast(float, (unsigned)u1.z << 16);
    v1[3] += __builtin_bit_cast(float, (unsigned)u1.w << 16);
  }
  float p = 0.f;
  ushort4 st;
  unsigned short* sp = (unsigned short*)&st;
  #pragma unroll
  for (int e = 0; e < 4; ++e) {
    float v = v0[e] * (1.0f - w) + v1[e] * w;
    sp[e] = f2bf(v);
    p += v * v;
  }
  *(ushort4*)&x2b[(size_t)row * 256 + c] = st;
  #pragma unroll
  for (int m = 32; m > 0; m >>= 1) p += __shfl_down(p, m, 64);
  if ((threadIdx.x & 63) == 0) sq[row] = p;
}

// ---------------- adj GEMM v2: fp32-A via global_load_lds, cvt at frag read ---
// hs_slice(z) = adj[:, z*512:+512] @ Tt[:, same]^T. BM=64, BN=256 (full N),
// 4 waves 1x4 (wave 64x64). LDS: A fp32 16KB + B bf16 32KB = 48KB -> 3 blk/CU.
// Both operands fire-and-forget glds (gram structure) - no reg round-trip.
__launch_bounds__(256)
__global__ void adj_gemm_kernel(const float* __restrict__ adjp,
                                const unsigned short* __restrict__ Ttp,
                                unsigned short* __restrict__ hs) {
  constexpr int NT = 8;                        // KT = 512
  __shared__ alignas(16) float Asf[64 * 64];   // fp32 A tile, 16 chunks/row
  __shared__ alignas(16) unsigned short Bs[256 * 64];

  const int tid = threadIdx.x;
  const int wid = tid >> 6;
  const int lane = tid & 63;
  const int g = lane >> 4, lr = lane & 15;
  const int m0 = blockIdx.x * 64;
  const int kbase = blockIdx.y * 512;
  unsigned short* outp = hs + (size_t)blockIdx.y * 4096 * 256;

  // A staging: slot s = it*256+tid; row = it*16 + (tid>>4); chunk cp = tid&15;
  // swizzled source chunk sc = cp ^ (row&7); (row&7) == ((tid>>4)&7) across it.
  const int arow = tid >> 4;                   // 0..15
  const int acp = tid & 15;
  const int asc = acp ^ (arow & 7);
  const float* aB[4];
  #pragma unroll
  for (int it = 0; it < 4; ++it)
    aB[it] = adjp + (size_t)(m0 + it * 16 + arow) * 4096 + kbase + asc * 4;
  float* const aDst = Asf + (size_t)wid * 256;          // + it*1024 floats

  // B staging (bf16): row = it*32 + (tid>>3), chunk = tid&7, swizzled
  const int brow = tid >> 3;                   // 0..31
  const int bsc = (tid & 7) ^ (brow & 7);
  const unsigned short* bBase = Ttp + (size_t)brow * 4096 + kbase + bsc * 8;
  unsigned short* const bDst = Bs + (size_t)wid * 512;  // + it*2048 elems

  f32x4 acc[4][4];
  const f32x4 fzero = {0.f, 0.f, 0.f, 0.f};
  #pragma unroll
  for (int i = 0; i < 4; ++i)
    #pragma unroll
    for (int j = 0; j < 4; ++j) acc[i][j] = fzero;

  const float4* Asf4 = (const float4*)Asf;

  #pragma unroll
  for (int t = 0; t < NT; ++t) {
    #pragma unroll
    for (int it = 0; it < 8; ++it)
      GLDS(bBase + (size_t)it * 32 * 4096 + t * 64, bDst + it * 2048);
    #pragma unroll
    for (int it = 0; it < 4; ++it)
      GLDS(aB[it] + t * 64, aDst + it * 1024);
    __syncthreads();
    #pragma unroll
    for (int kk = 0; kk < 2; ++kk) {
      const int chb = (kk * 4 + g) ^ (lr & 7);
      bf16x8 b[4];
      #pragma unroll
      for (int j = 0; j < 4; ++j)
        b[j] = *(const bf16x8*)&Bs[(wid * 64 + j * 16 + lr) * 64 + chb * 8];
      const int c0 = kk * 8 + g * 2;
      #pragma unroll
      for (int i = 0; i < 4; ++i) {
        const int row = i * 16 + lr;
        float4 f0 = Asf4[row * 16 + (c0 ^ (lr & 7))];
        float4 f1 = Asf4[row * 16 + ((c0 + 1) ^ (lr & 7))];
        uint4 pk = { pack2(f0.x, f0.y), pack2(f0.z, f0.w),
                     pack2(f1.x, f1.y), pack2(f1.z, f1.w) };
        bf16x8 a = __builtin_bit_cast(bf16x8, pk);
        #pragma unroll
        for (int j = 0; j < 4; ++j)
          acc[i][j] = __builtin_amdgcn_mfma_f32_16x16x32_bf16(a, b[j], acc[i][j], 0, 0, 0);
      }
    }
    __syncthreads();
  }

  // epilogue: bf16 [4096][256] slice
  #pragma unroll
  for (int i = 0; i < 4; ++i) {
    int mrow = m0 + i * 16 + g * 4;
    #pragma unroll
    for (int j = 0; j < 4; ++j) {
      int col = wid * 64 + j * 16 + lr;
      #pragma unroll
      for (int r = 0; r < 4; ++r)
        outp[(size_t)(mrow + r) * 256 + col] = f2bf(acc[i][j][r]);
    }
  }
}

// ---------------- Gram + fused symmetric argmin, 128^2 tile ------------------
__launch_bounds__(256, 3)
__global__ void gram_kernel(const unsigned short* __restrict__ X,
                            const float* __restrict__ sq,
                            unsigned* __restrict__ pv) {
  __shared__ alignas(16) unsigned short As[128 * 64];
  __shared__ alignas(16) unsigned short Bs[128 * 64];
  __shared__ unsigned mrgr[2][128];
  __shared__ unsigned mrgc[2][128];

  const int tid = threadIdx.x;
  const int wid = tid >> 6;
  const int lane = tid & 63;
  const int g = lane >> 4, lr = lane & 15;
  const int wr = wid >> 1, wc = wid & 1;

  int t = blockIdx.x;            // triangular decode, bj <= bi
  int bi = (int)((sqrtf(8.0f * (float)t + 1.0f) - 1.0f) * 0.5f);
  while ((bi + 1) * (bi + 2) / 2 <= t) ++bi;
  while (bi * (bi + 1) / 2 > t) --bi;
  const int bx = bi;
  const int by = t - bi * (bi + 1) / 2;
  const int m0 = bx * 128;
  const int n0 = by * 128;
  const bool diag = (bx == by);

  const int srow = tid >> 3;
  const int ssc = (tid & 7) ^ (srow & 7);
  const unsigned short* aBase = X + (size_t)(m0 + srow) * 256 + ssc * 8;
  const unsigned short* bBase = X + (size_t)(n0 + srow) * 256 + ssc * 8;
  unsigned short* const aDst = As + (size_t)(tid >> 6) * 512;
  unsigned short* const bDst = Bs + (size_t)(tid >> 6) * 512;
  const unsigned short* const Bsrc = diag ? As : Bs;   // uniform select

  f32x4 acc[4][4];
  const f32x4 fzero = {0.f, 0.f, 0.f, 0.f};
  #pragma unroll
  for (int i = 0; i < 4; ++i)
    #pragma unroll
    for (int j = 0; j < 4; ++j) acc[i][j] = fzero;

  #pragma unroll
  for (int ks = 0; ks < 4; ++ks) {
    #pragma unroll
    for (int it = 0; it < 4; ++it)
      GLDS(aBase + it * 8192 + ks * 64, aDst + it * 2048);
    if (!diag) {
      #pragma unroll
      for (int it = 0; it < 4; ++it)
        GLDS(bBase + it * 8192 + ks * 64, bDst + it * 2048);
    }
    __syncthreads();
    #pragma unroll
    for (int kk = 0; kk < 2; ++kk) {
      const int ch = (kk * 4 + g) ^ (lr & 7);       // row&7 == lr&7 for all frags
      bf16x8 b[4];
      #pragma unroll
      for (int j = 0; j < 4; ++j)
        b[j] = *(const bf16x8*)&Bsrc[(wc * 64 + j * 16 + lr) * 64 + ch * 8];
      #pragma unroll
      for (int i = 0; i < 4; ++i) {
        bf16x8 a = *(const bf16x8*)&As[(wr * 64 + i * 16 + lr) * 64 + ch * 8];
        #pragma unroll
        for (int j = 0; j < 4; ++j)
          acc[i][j] = __builtin_amdgcn_mfma_f32_16x16x32_bf16(a, b[j], acc[i][j], 0, 0, 0);
      }
    }
    __syncthreads();
  }

  int jcol[4];
  float sqj[4];
  unsigned ckey[4];
  #pragma unroll
  for (int j = 0; j < 4; ++j) {
    jcol[j] = n0 + wc * 64 + j * 16 + lr;
    sqj[j] = sq[jcol[j]];
    ckey[j] = 0xFFFFFFFFu;
  }
  #pragma unroll
  for (int i = 0; i < 4; ++i) {
    #pragma unroll
    for (int r = 0; r < 4; ++r) {
      const int lrow = wr * 64 + i * 16 + g * 4 + r;
      const int irow = m0 + lrow;
      const float sqi = sq[irow];
      unsigned rk = 0xFFFFFFFFu;
      #pragma unroll
      for (int j = 0; j < 4; ++j) {
        float v = fmaf(-2.0f, acc[i][j][r], sqi + sqj[j]);   // true d2 >= 0
        unsigned bits = __float_as_uint(v) & 0xFFFFE000u;
        unsigned krow = bits | (unsigned)jcol[j];
        if (diag && jcol[j] == irow) krow = 0xFFFFFFFFu;
        rk = min(rk, krow);
        if (!diag) ckey[j] = min(ckey[j], bits | (unsigned)irow);
      }
      #pragma unroll
      for (int m = 1; m < 16; m <<= 1)
        rk = min(rk, (unsigned)__shfl_xor((int)rk, m, 64));
      if (lr == 0) mrgr[wc][lrow] = rk;
    }
  }
  if (!diag) {
    #pragma unroll
    for (int j = 0; j < 4; ++j) {
      ckey[j] = min(ckey[j], (unsigned)__shfl_xor((int)ckey[j], 16, 64));
      ckey[j] = min(ckey[j], (unsigned)__shfl_xor((int)ckey[j], 32, 64));
      if (g == 0) mrgc[wr][wc * 64 + j * 16 + lr] = ckey[j];
    }
  }
  __syncthreads();
  if (tid < 128) {
    pv[(size_t)by * 8192 + m0 + tid] = min(mrgr[0][tid], mrgr[1][tid]);
  } else if (!diag) {
    int c = tid - 128;
    pv[(size_t)(64 + bx) * 8192 + n0 + c] = min(mrgc[0][c], mrgc[1][c]);
  }
}

// ---------------- single-buffer GEMM-NT (C = A * B^T), unrolled K ------------
// EPI 0: Cf[m][n] fp32.  EPI 1: Ct[n][m] bf16 transposed.
// GATHER: inline per-block argmin-reduce over pv, then A row r reads row nn[r].
template <int BM, int BN, int WAVES_M, int KT, int EPI, bool AF32, bool GATHER>
__launch_bounds__(256)
__global__ void gemm_nt_kernel(const void* __restrict__ Ap, int lda,
                               const unsigned short* __restrict__ Bp, int ldb,
                               int M, int N,
                               float* __restrict__ Cf,
                               unsigned short* __restrict__ Cb,
                               const unsigned* __restrict__ pv) {
  constexpr int BK = 64;
  constexpr int NT = KT / BK;
  constexpr int WAVES_N = 4 / WAVES_M;
  constexpr int WM = BM / WAVES_M;
  constexpr int WN = BN / WAVES_N;
  constexpr int FM = WM / 16;
  constexpr int FN = WN / 16;
  constexpr int ASLOT = BM * 8;
  constexpr int AITER = (ASLOT + 255) / 256;
  constexpr int BITER = (BN * 8) / 256;

  __shared__ alignas(16) unsigned short As[BM * BK];
  __shared__ alignas(16) unsigned short Bs[BN * BK];
  __shared__ unsigned redp[GATHER ? 4 * 64 : 1];
  __shared__ unsigned pckl[GATHER ? 64 : 1];

  const int tid = threadIdx.x;
  const int wid = tid >> 6;
  const int lane = tid & 63;
  const int g = lane >> 4;
  const int lr = lane & 15;
  const int wr = wid / WAVES_N;
  const int wc = wid % WAVES_N;
  const int m0 = blockIdx.x * BM;
  const int n0 = blockIdx.y * BN;

  // ---- inline NN-index reduce (GATHER): rows m0..m0+63 share chunk cr ----
  if constexpr (GATHER) {
    static_assert(!GATHER || BM == 64, "inline reduce assumes BM==64");
    const int row = tid & 63;          // lane
    const int part = tid >> 6;         // wave
    const int cr = m0 >> 7;            // block-uniform chunk
    unsigned best = 0xFFFFFFFFu;
    #pragma unroll
    for (int s8 = 0; s8 < 16; ++s8) {
      int s = part * 16 + s8;
      int slot = s + (s > cr ? 64 : 0);
      best = min(best, pv[(size_t)slot * 8192 + m0 + row]);
    }
    redp[part * 64 + row] = best;
    __syncthreads();
    if (tid < 64)
      pckl[tid] = min(min(redp[tid], redp[64 + tid]),
                      min(redp[128 + tid], redp[192 + tid])) & 0x1FFFu;
    __syncthreads();
  }

  const int srow = tid >> 3;
  const int ssc = (tid & 7) ^ (srow & 7);
  const float* aBF[AITER];
  const unsigned short* aBH[AITER];
  #pragma unroll
  for (int it = 0; it < AITER; ++it) {
    int r = m0 + srow + it * 32;
    if constexpr (AF32) {
      aBF[it] = (const float*)Ap + (size_t)r * (size_t)lda + ssc * 8;
    } else {
      int sr = GATHER ? (int)pckl[srow + it * 32] : r;
      aBH[it] = (const unsigned short*)Ap + (size_t)sr * (size_t)lda + ssc * 8;
    }
  }
  const unsigned short* bBase = Bp + (size_t)(n0 + srow) * (size_t)ldb + ssc * 8;
  unsigned short* const sDst = As + (size_t)wid * 512;
  unsigned short* const bDst = Bs + (size_t)wid * 512;

  f32x4 acc[FM][FN];
  const f32x4 fzero = {0.f, 0.f, 0.f, 0.f};
  #pragma unroll
  for (int i = 0; i < FM; ++i)
    #pragma unroll
    for (int j = 0; j < FN; ++j) acc[i][j] = fzero;

  #pragma unroll
  for (int t = 0; t < NT; ++t) {
    #pragma unroll
    for (int it = 0; it < BITER; ++it)
      GLDS(bBase + (size_t)it * 32 * ldb + t * 64, bDst + it * 2048);
    if constexpr (AF32) {
      #pragma unroll
      for (int it = 0; it < AITER; ++it) {
        if (ASLOT % 256 == 0 || it * 256 + tid < ASLOT) {
          const float* src = aBF[it] + t * 64;
          float4 f0 = *(const float4*)src;
          float4 f1 = *(const float4*)(src + 4);
          uint4 pk = { pack2(f0.x, f0.y), pack2(f0.z, f0.w),
                       pack2(f1.x, f1.y), pack2(f1.z, f1.w) };
          *(uint4*)&As[(it * 32 + srow) * BK + (tid & 7) * 8] = pk;
        }
      }
    } else {
      #pragma unroll
      for (int it = 0; it < AITER; ++it)
        GLDS(aBH[it] + t * 64, sDst + it * 2048);
    }
    __syncthreads();
    #pragma unroll
    for (int kk = 0; kk < 2; ++kk) {
      const int ch = (kk * 4 + g) ^ (lr & 7);
      bf16x8 a[FM], b[FN];
      #pragma unroll
      for (int i = 0; i < FM; ++i)
        a[i] = *(const bf16x8*)&As[(wr * WM + i * 16 + lr) * BK + ch * 8];
      #pragma unroll
      for (int j = 0; j < FN; ++j)
        b[j] = *(const bf16x8*)&Bs[(wc * WN + j * 16 + lr) * BK + ch * 8];
      #pragma unroll
      for (int i = 0; i < FM; ++i)
        #pragma unroll
        for (int j = 0; j < FN; ++j)
          acc[i][j] = __builtin_amdgcn_mfma_f32_16x16x32_bf16(a[i], b[j], acc[i][j], 0, 0, 0);
    }
    __syncthreads();
  }

  const int rowb = wr * WM;
  const int colb = wc * WN;
  if constexpr (EPI == 0) {
    #pragma unroll
    for (int i = 0; i < FM; ++i) {
      int mrow = m0 + rowb + i * 16 + g * 4;
      #pragma unroll
      for (int j = 0; j < FN; ++j) {
        int col = n0 + colb + j * 16 + lr;
        #pragma unroll
        for (int r = 0; r < 4; ++r)
          Cf[(size_t)(mrow + r) * N + col] = acc[i][j][r];
      }
    }
  } else {
    #pragma unroll
    for (int i = 0; i < FM; ++i) {
      int mrow = m0 + rowb + i * 16 + g * 4;
      #pragma unroll
      for (int j = 0; j < FN; ++j) {
        int col = n0 + colb + j * 16 + lr;
        ushort4 st;
        st.x = f2bf(acc[i][j][0]);
        st.y = f2bf(acc[i][j][1]);
        st.z = f2bf(acc[i][j][2]);
        st.w = f2bf(acc[i][j][3]);
        *(ushort4*)&Cb[(size_t)col * M + mrow] = st;
      }
    }
  }
}

// ---------------- launch ----------------

extern "C" void kernel_launch(void* const* d_in, const int* in_sizes, int n_in,
                              void* d_out, int out_size, void* d_ws, size_t ws_size,
                              hipStream_t stream) {
  (void)in_sizes; (void)n_in; (void)out_size; (void)ws_size;
  const float* x   = (const float*)d_in[0];   // [4096][256]
  const float* adj = (const float*)d_in[1];   // [4096][4096]
  const float* W1  = (const float*)d_in[2];   // [256][256]
  const float* W2  = (const float*)d_in[3];   // [256][256]
  float* out = (float*)d_out;                 // [8192][256]

  char* p = (char*)d_ws;
  unsigned short* Tt  = (unsigned short*)p;  p += 4096 * 256 * 2;     // 2MB
  char* R             = p;                   p += 16 * 1024 * 1024;   // hs(16MB)/pv(4MB)
  unsigned short* x2b = (unsigned short*)p;  p += 8192 * 256 * 2;     // 4MB
  float* sqv          = (float*)p;           p += 8192 * 4;
  unsigned short* W1t = (unsigned short*)p;  p += 256 * 256 * 2;
  unsigned short* W2t = (unsigned short*)p;  p += 256 * 256 * 2;

  // region R overlays (disjoint lifetimes):
  unsigned short* hs = (unsigned short*)R;   // [8][4096][256] bf16, 16MB
  unsigned* pv       = (unsigned*)R;         // [128][8192] u32 keys, 4MB

  transpose_w_kernel<<<256, 256, 0, stream>>>(W1, W2, W1t, W2t);

  // Tt = (x @ W1)^T : M=4096 N=256 K=256 (EPI1 transposed bf16 out)
  gemm_nt_kernel<64, 64, 4, 256, 1, true, false><<<dim3(64, 4), 256, 0, stream>>>(
      x, 256, W1t, 256, 4096, 256, nullptr, Tt, nullptr);

  // h(k-split) = adj @ Tt^T : fp32-A via glds, cvt at fragment read.
  // 512 blocks, 48KB LDS -> 3 blocks/CU.
  adj_gemm_kernel<<<dim3(64, 8), 256, 0, stream>>>(adj, Tt, hs);

  upsample_kernel<<<2048, 256, 0, stream>>>(hs, x2b, sqv);

  // gram triangle (2080 blocks); pv needs NO init (bounded inline reduce)
  gram_kernel<<<2080, 256, 0, stream>>>(x2b, sqv, pv);

  // out = x2[nn] @ W2 : inline argmin-reduce + gathered-A GEMM -> d_out
  gemm_nt_kernel<64, 64, 4, 256, 0, false, true><<<dim3(128, 4), 256, 0, stream>>>(
      x2b, 256, W2t, 256, 8192, 256, out, nullptr, pv);
}